// Round 9
// baseline (235.457 us; speedup 1.0000x reference)
//
#include <hip/hip_runtime.h>
#include <hip/hip_bf16.h>
#include <math.h>

// Problem constants
#define BB 4
#define CIN 64
#define CH 32
#define HH 64
#define WW 64
#define NN 4096           // H*W
#define MCH 4
#define NQCH 32           // q-chunks for column stats (chunk = 128 queries)
#define LOG2E 1.4426950408889634f

// ws layout (floats). Total 1,229,824 floats = 4.69 MiB (proven size).
// Temporal aliasing chain (stream order): CPSUM (k2a->k2b) ; T8 (k3a->k3b)
// aliases XA+XB+CPSUM region; XA written k4; XB written k5.
#define PP_OFF     0          // 1024
#define Q4_OFF     1024       // 65536  (Q pre-scaled by LOG2E)
#define K4_OFF     66560      // 65536
#define CV_OFF     132096     // 16384  (c' in log2 domain)
#define CPSUM_OFF  672768     // 524288 (dead after k2b)
#define RMAP_OFF   148480     // 16384
#define CMAPF_OFF  164864     // 16384
#define T8_OFF     181248     // 1048576 (XA+XB region; dead after k3b)
#define XA_OFF     181248     // 524288
#define XB_OFF     705536     // 524288
// end = 1229824 floats

// out layout (FLOAT32 elements): x | out | corrected_map
#define OUT_X_OFF   0
#define OUT_O_OFF   524288
#define OUT_CM_OFF  540672

__device__ __forceinline__ float bilin32(const float* src, int b, int y, int x) {
    float sy = 0.5f * y - 0.25f;
    float sx = 0.5f * x - 0.25f;
    float fy0 = floorf(sy), fx0 = floorf(sx);
    int y0 = (int)fy0, x0 = (int)fx0;
    float fy = sy - fy0, fx = sx - fx0;
    int y0c = min(max(y0, 0), 31), y1c = min(max(y0 + 1, 0), 31);
    int x0c = min(max(x0, 0), 31), x1c = min(max(x0 + 1, 0), 31);
    const float* p = src + b * 1024;
    float v00 = p[y0c * 32 + x0c], v01 = p[y0c * 32 + x1c];
    float v10 = p[y1c * 32 + x0c], v11 = p[y1c * 32 + x1c];
    float v0 = v00 + fx * (v01 - v00);
    float v1 = v10 + fx * (v11 - v10);
    return v0 + fy * (v1 - v0);
}

// K0: pos embedding projected through wq/wk, per coordinate (exact).
__global__ void k0_posproj(const float* __restrict__ wq, const float* __restrict__ wk,
                           float* __restrict__ pp) {
    int t = threadIdx.x;  // coordinate 0..63
    float coord = (float)(t + 1);
    float qy[4] = {0,0,0,0}, qx[4] = {0,0,0,0}, ky[4] = {0,0,0,0}, kx[4] = {0,0,0,0};
    for (int c = 0; c < 32; ++c) {
        float e = (2.0f * (float)(c / 2)) / 32.0f;
        float dim = powf(10000.0f, e);
        float ang = coord / dim;
        float pr = (c & 1) ? cosf(ang) : sinf(ang);
        #pragma unroll
        for (int m = 0; m < 4; ++m) {
            qy[m] += wq[m * 64 + c] * pr;
            qx[m] += wq[m * 64 + 32 + c] * pr;
            ky[m] += wk[m * 64 + c] * pr;
            kx[m] += wk[m * 64 + 32 + c] * pr;
        }
    }
    #pragma unroll
    for (int m = 0; m < 4; ++m) {
        pp[0 * 256 + m * 64 + t] = qy[m];
        pp[1 * 256 + m * 64 + t] = qx[m];
        pp[2 * 256 + m * 64 + t] = ky[m];
        pp[3 * 256 + m * 64 + t] = kx[m];
    }
}

// K1: Q/K projections, channel-split 4x16 + LDS reduce. grid = B*N/64 = 256
// Q is written PRE-SCALED by LOG2E (exp2 domain); K natural.
__global__ void k1_qk(const float* __restrict__ fq, const float* __restrict__ fk,
                      const float* __restrict__ wq, const float* __restrict__ wk,
                      const float* __restrict__ pp,
                      float* __restrict__ Q4, float* __restrict__ K4) {
    __shared__ float wqs[256], wks[256];
    __shared__ float red[256][9];
    int tid = threadIdx.x;
    wqs[tid] = wq[tid];
    wks[tid] = wk[tid];
    __syncthreads();
    int qi = tid & 63, g = tid >> 6;
    int gid = blockIdx.x * 64 + qi;
    int b = gid >> 12, hw = gid & 4095;
    const float* fqb = fq + (size_t)b * CIN * NN + hw;
    const float* fkb = fk + (size_t)b * CIN * NN + hw;
    float aq[4] = {0,0,0,0}, ak[4] = {0,0,0,0};
    int c0 = g * 16;
    #pragma unroll 4
    for (int c = c0; c < c0 + 16; ++c) {
        float vq = fqb[c * NN];
        float vk = fkb[c * NN];
        #pragma unroll
        for (int m = 0; m < 4; ++m) {
            aq[m] += wqs[m * 64 + c] * vq;
            ak[m] += wks[m * 64 + c] * vk;
        }
    }
    #pragma unroll
    for (int m = 0; m < 4; ++m) { red[tid][m] = aq[m]; red[tid][4 + m] = ak[m]; }
    __syncthreads();
    if (tid < 64) {
        int y = hw >> 6, x = hw & 63;
        float q4[4], k4[4];
        #pragma unroll
        for (int m = 0; m < 4; ++m) {
            q4[m] = LOG2E * (red[tid][m] + red[tid + 64][m] + red[tid + 128][m] + red[tid + 192][m]
                  + pp[0 * 256 + m * 64 + y] + pp[1 * 256 + m * 64 + x]);
            k4[m] = red[tid][4 + m] + red[tid + 64][4 + m] + red[tid + 128][4 + m] + red[tid + 192][4 + m]
                  + pp[2 * 256 + m * 64 + y] + pp[3 * 256 + m * 64 + x];
        }
        ((float4*)Q4)[gid] = make_float4(q4[0], q4[1], q4[2], q4[3]);
        ((float4*)K4)[gid] = make_float4(k4[0], k4[1], k4[2], k4[3]);
    }
}

// K2a: per-(b, q-chunk of 128) column sum of exp(sim) = 2^(q'.k), direct.
// 2 keys/thread. grid = B*NQCH*8 = 1024, block 256.
__global__ void k2a_colstats(const float* __restrict__ Q4, const float* __restrict__ K4,
                             float* __restrict__ cpsum) {
    __shared__ float4 Qs[128];
    int blk = blockIdx.x;
    int kblk = blk & 7;   blk >>= 3;
    int qch  = blk & 31;  blk >>= 5;
    int b    = blk;
    int tid = threadIdx.x;
    if (tid < 128)
        Qs[tid] = ((const float4*)Q4)[b * NN + qch * 128 + tid];
    __syncthreads();
    int k0 = kblk * 512 + tid;
    float4 kva = ((const float4*)K4)[b * NN + k0];
    float4 kvb = ((const float4*)K4)[b * NN + k0 + 256];
    float sa = 0.0f, sb = 0.0f;
    #pragma unroll 8
    for (int i = 0; i < 128; ++i) {
        float4 q = Qs[i];
        float da = fmaf(q.x, kva.x, fmaf(q.y, kva.y, fmaf(q.z, kva.z, q.w * kva.w)));
        float db = fmaf(q.x, kvb.x, fmaf(q.y, kvb.y, fmaf(q.z, kvb.z, q.w * kvb.w)));
        sa += exp2f(da);
        sb += exp2f(db);
    }
    cpsum[(b * NQCH + qch) * NN + k0] = sa;
    cpsum[(b * NQCH + qch) * NN + k0 + 256] = sb;
}

// K2b: merge chunk sums -> c'[b][k] = LOG2E*(m_k_r - 1) - log2(colsum)
__global__ void k2b_cmerge(const float* __restrict__ cpsum,
                           const float* __restrict__ m_k, float* __restrict__ cvals) {
    int gid = blockIdx.x * 256 + threadIdx.x;  // B*N
    int b = gid >> 12, k = gid & 4095;
    float S = 0.0f;
    #pragma unroll
    for (int j = 0; j < NQCH; ++j) S += cpsum[(b * NQCH + j) * NN + k];
    float mk = bilin32(m_k, b, k >> 6, k & 63);
    cvals[gid] = LOG2E * (mk - 1.0f) - log2f(S);
}

// K3a: lane-per-query chunk scan. Block = 4 waves, all sharing one LDS-staged
// 512-key chunk (broadcast ds_reads). Each lane owns 1 query: float4 q + 8-reg
// sorted top-8 (no arrays -> no spill). grid = B*16*8 = 512.
__global__ void k3a_scan(const float* __restrict__ Q4, const float* __restrict__ K4,
                         const float* __restrict__ cvals, float* __restrict__ t8) {
    __shared__ float4 kvs[512];   // 8 KB
    __shared__ float  cvs[512];   // 2 KB
    int blk = blockIdx.x;
    int kc = blk & 7;   blk >>= 3;
    int g2 = blk & 15;  blk >>= 4;
    int b  = blk;
    int tid = threadIdx.x;
    int wave = tid >> 6, lane = tid & 63;

    const float4* Kb = (const float4*)K4 + b * NN + kc * 512;
    const float* cb = cvals + b * NN + kc * 512;
    #pragma unroll
    for (int i = tid; i < 512; i += 256) {
        kvs[i] = Kb[i];
        cvs[i] = cb[i];
    }
    __syncthreads();

    int qrow = (g2 * 4 + wave) * 64 + lane;
    float4 qv = ((const float4*)Q4)[b * NN + qrow];
    float t0 = -1e30f, t1 = -1e30f, t2 = -1e30f, t3 = -1e30f;
    float t4 = -1e30f, t5 = -1e30f, t6 = -1e30f, t7 = -1e30f;  // ascending
    #pragma unroll 4
    for (int i = 0; i < 512; ++i) {
        float4 kv = kvs[i];
        float s = fmaf(qv.x, kv.x, fmaf(qv.y, kv.y,
                  fmaf(qv.z, kv.z, fmaf(qv.w, kv.w, cvs[i]))));
        if (s > t0) {
            float a = fmaxf(t0, s);
            t0 = fminf(a, t1); a = fmaxf(a, t1);
            t1 = fminf(a, t2); a = fmaxf(a, t2);
            t2 = fminf(a, t3); a = fmaxf(a, t3);
            t3 = fminf(a, t4); a = fmaxf(a, t4);
            t4 = fminf(a, t5); a = fmaxf(a, t5);
            t5 = fminf(a, t6); a = fmaxf(a, t6);
            t6 = fminf(a, t7); t7 = fmaxf(a, t7);
        }
    }
    float* o = t8 + ((size_t)(b * NN + qrow)) * 64 + kc * 8;
    o[0] = t0; o[1] = t1; o[2] = t2; o[3] = t3;
    o[4] = t4; o[5] = t5; o[6] = t6; o[7] = t7;
}

// K3b: merge 8 chunk-top8s (64 candidates) -> global top-8 -> cm/rmap.
// Wave per query; lane holds one candidate; 8-round argmax-pop (verified).
__global__ void k3b_merge(const float* __restrict__ t8, const float* __restrict__ mapin,
                          float* __restrict__ rmap, float* __restrict__ cmapf,
                          float* __restrict__ outp) {
    int tid = threadIdx.x;
    int qid = blockIdx.x * 4 + (tid >> 6);   // 0 .. B*N-1
    int lane = tid & 63;
    float v = t8[(size_t)qid * 64 + lane];
    float sm = 0.0f;
    #pragma unroll
    for (int r = 0; r < 8; ++r) {
        float m = v;
        int ln = lane;
        #pragma unroll
        for (int off = 32; off >= 1; off >>= 1) {
            float om = __shfl_xor(m, off);
            int ol = __shfl_xor(ln, off);
            if (om > m || (om == m && ol < ln)) { m = om; ln = ol; }
        }
        sm += exp2f(m);
        if (lane == ln) v = -1e30f;
    }
    if (lane == 0) {
        float cmv = sm * 0.125f;
        int b = qid >> 12, hw = qid & 4095;
        float mr = bilin32(mapin, b, hw >> 6, hw & 63);
        float cm = cmv * mr + mr;
        float rm = 1.0f / (1.0f + __expf(cm));
        rmap[qid] = rm;
        cmapf[qid] = cm;
        outp[OUT_CM_OFF + qid] = cm;
    }
}

// K4: x1 = conv1x1(rmap*f, w_in) + b_in. og-split 8 -> grid 512
__global__ void k4_conv1(const float* __restrict__ f, const float* __restrict__ rmap,
                         const float* __restrict__ w_in, const float* __restrict__ b_in,
                         float* __restrict__ xout) {
    __shared__ float ws_[1024];
    __shared__ float bs[32];
    int tid = threadIdx.x;
    for (int i = tid; i < 1024; i += 256) ws_[i] = w_in[i];
    if (tid < 32) bs[tid] = b_in[tid];
    __syncthreads();
    int gid = blockIdx.x * 256 + tid;      // b(2b) og(3b) hw(12b)
    int hw = gid & 4095;
    int og = (gid >> 12) & 7;
    int b  = gid >> 15;
    float rm = rmap[b * NN + hw];
    float acc[4];
    #pragma unroll
    for (int j = 0; j < 4; ++j) acc[j] = bs[og * 4 + j];
    const float* fb = f + (size_t)b * CH * NN + hw;
    for (int i = 0; i < 32; ++i) {
        float v = fb[i * NN] * rm;
        #pragma unroll
        for (int j = 0; j < 4; ++j) acc[j] += ws_[(og * 4 + j) * 32 + i] * v;
    }
    float* xo = xout + (size_t)b * CH * NN + (og * 4) * NN + hw;
    #pragma unroll
    for (int j = 0; j < 4; ++j) xo[j * NN] = acc[j];
}

// K5: 3x3 conv 32->32 (+bias, relu). og-split 8 -> grid = b*ty*tx*og = 512
__global__ void k5_conv3(const float* __restrict__ xin, const float* __restrict__ w,
                         const float* __restrict__ bias, float* __restrict__ xout,
                         float* __restrict__ outx) {
    __shared__ float tile[32][324];   // 18x18 per channel
    __shared__ float wsm[1152];       // 4 o x 32 i x 9
    __shared__ float bsm[4];
    int blk = blockIdx.x;
    int og = blk & 7;  blk >>= 3;
    int tx = blk & 3;  blk >>= 2;
    int ty = blk & 3;  blk >>= 2;
    int b  = blk;
    int tid = threadIdx.x;
    for (int i = tid; i < 1152; i += 256) wsm[i] = w[og * 1152 + i];
    if (tid < 4) bsm[tid] = bias[og * 4 + tid];
    int y0 = ty * 16 - 1, x0 = tx * 16 - 1;
    for (int i = tid; i < 32 * 324; i += 256) {
        int c = i / 324, r = i % 324;
        int yy = r / 18, xx = r % 18;
        int gy = y0 + yy, gx = x0 + xx;
        float v = 0.0f;
        if (gy >= 0 && gy < 64 && gx >= 0 && gx < 64)
            v = xin[((size_t)b * CH + c) * NN + gy * 64 + gx];
        tile[c][r] = v;
    }
    __syncthreads();
    int py = tid >> 4, px = tid & 15;
    float acc[4];
    #pragma unroll
    for (int j = 0; j < 4; ++j) acc[j] = bsm[j];
    for (int i = 0; i < 32; ++i) {
        const float* tr = &tile[i][py * 18 + px];
        float v00 = tr[0],  v01 = tr[1],  v02 = tr[2];
        float v10 = tr[18], v11 = tr[19], v12 = tr[20];
        float v20 = tr[36], v21 = tr[37], v22 = tr[38];
        #pragma unroll
        for (int j = 0; j < 4; ++j) {
            const float* wj = &wsm[j * 288 + i * 9];
            acc[j] += v00 * wj[0] + v01 * wj[1] + v02 * wj[2]
                    + v10 * wj[3] + v11 * wj[4] + v12 * wj[5]
                    + v20 * wj[6] + v21 * wj[7] + v22 * wj[8];
        }
    }
    size_t base = (size_t)b * CH * NN + (size_t)(og * 4) * NN
                + (ty * 16 + py) * 64 + tx * 16 + px;
    #pragma unroll
    for (int j = 0; j < 4; ++j) {
        float r_ = fmaxf(acc[j], 0.0f);
        xout[base + j * NN] = r_;
        if (outx) outx[base + j * NN] = r_;
    }
}

// K6: final 3x3 conv 32->1 + b_out + corrected_map. channel-split 4x8, grid 256
__global__ void k6_convout(const float* __restrict__ xin, const float* __restrict__ w_out,
                           const float* __restrict__ b_out, const float* __restrict__ cmapf,
                           float* __restrict__ outp) {
    __shared__ float wsm[288];
    __shared__ float red[256];
    int tid = threadIdx.x;
    for (int i = tid; i < 288; i += 256) wsm[i] = w_out[i];
    int pxi = tid & 63, g = tid >> 6;
    int gid = blockIdx.x * 64 + pxi;   // B*N over 256 blocks
    int b = gid >> 12, hw = gid & 4095;
    int y = hw >> 6, x = hw & 63;
    __syncthreads();
    float acc = 0.0f;
    int c0 = g * 8;
    for (int i = c0; i < c0 + 8; ++i) {
        const float* xi = xin + ((size_t)b * CH + i) * NN;
        #pragma unroll
        for (int ky = 0; ky < 3; ++ky) {
            int gy = y + ky - 1;
            if (gy < 0 || gy > 63) continue;
            #pragma unroll
            for (int kx = 0; kx < 3; ++kx) {
                int gx = x + kx - 1;
                if (gx < 0 || gx > 63) continue;
                acc += xi[gy * 64 + gx] * wsm[i * 9 + ky * 3 + kx];
            }
        }
    }
    red[tid] = acc;
    __syncthreads();
    if (tid < 64) {
        float a = red[tid] + red[tid + 64] + red[tid + 128] + red[tid + 192]
                + b_out[0] + cmapf[gid];
        outp[OUT_O_OFF + gid] = a;
    }
}

extern "C" void kernel_launch(void* const* d_in, const int* in_sizes, int n_in,
                              void* d_out, int out_size, void* d_ws, size_t ws_size,
                              hipStream_t stream) {
    const float* f     = (const float*)d_in[0];
    const float* mapin = (const float*)d_in[1];
    const float* f_q   = (const float*)d_in[2];
    const float* f_k   = (const float*)d_in[3];
    const float* m_k   = (const float*)d_in[4];
    const float* wq    = (const float*)d_in[5];
    const float* wk    = (const float*)d_in[6];
    const float* w_in  = (const float*)d_in[7];
    const float* b_in  = (const float*)d_in[8];
    const float* w_mid = (const float*)d_in[9];
    const float* b_mid = (const float*)d_in[10];
    const float* w_out = (const float*)d_in[11];
    const float* b_out = (const float*)d_in[12];
    float* outp = (float*)d_out;
    float* ws = (float*)d_ws;

    float* PP    = ws + PP_OFF;
    float* Q4    = ws + Q4_OFF;
    float* K4    = ws + K4_OFF;
    float* CV    = ws + CV_OFF;
    float* CPSUM = ws + CPSUM_OFF;
    float* RMAP  = ws + RMAP_OFF;
    float* CMAPF = ws + CMAPF_OFF;
    float* T8    = ws + T8_OFF;
    float* XA    = ws + XA_OFF;
    float* XB    = ws + XB_OFF;

    k0_posproj<<<1, 64, 0, stream>>>(wq, wk, PP);
    k1_qk<<<256, 256, 0, stream>>>(f_q, f_k, wq, wk, PP, Q4, K4);
    k2a_colstats<<<BB * NQCH * 8, 256, 0, stream>>>(Q4, K4, CPSUM);
    k2b_cmerge<<<64, 256, 0, stream>>>(CPSUM, m_k, CV);
    k3a_scan<<<BB * 16 * 8, 256, 0, stream>>>(Q4, K4, CV, T8);
    k3b_merge<<<BB * NN / 4, 256, 0, stream>>>(T8, mapin, RMAP, CMAPF, outp);
    k4_conv1<<<512, 256, 0, stream>>>(f, RMAP, w_in, b_in, XA);
    k5_conv3<<<512, 256, 0, stream>>>(XA, w_mid + 0 * 9216, b_mid + 0 * 32, XB, (float*)0);
    k5_conv3<<<512, 256, 0, stream>>>(XB, w_mid + 1 * 9216, b_mid + 1 * 32, XA, (float*)0);
    k5_conv3<<<512, 256, 0, stream>>>(XA, w_mid + 2 * 9216, b_mid + 2 * 32, XB, outp + OUT_X_OFF);
    k6_convout<<<256, 256, 0, stream>>>(XB, w_out, b_out, CMAPF, outp);
}

// Round 10
// 229.289 us; speedup vs baseline: 1.0269x; 1.0269x over previous
//
#include <hip/hip_runtime.h>
#include <hip/hip_bf16.h>
#include <math.h>

// Problem constants
#define BB 4
#define CIN 64
#define CH 32
#define HH 64
#define WW 64
#define NN 4096           // H*W
#define MCH 4
#define NQCH 32           // q-chunks for column stats (chunk = 128 queries)
#define LOG2E 1.4426950408889634f

// ws layout (floats). Total 1,229,824 floats = 4.69 MiB (proven size).
#define PP_OFF     0          // 1024
#define Q4_OFF     1024       // 65536  (Q pre-scaled by LOG2E)
#define K4_OFF     66560      // 65536
#define CV_OFF     132096     // 16384  (c' in log2 domain)
#define CPSUM_OFF  672768     // 524288 (dead after k2b)
#define RMAP_OFF   148480     // 16384
#define CMAPF_OFF  164864     // 16384
#define T8_OFF     181248     // 1048576 (XA+XB region; dead after k3b)
#define XA_OFF     181248     // 524288
#define XB_OFF     705536     // 524288

// out layout (FLOAT32 elements): x | out | corrected_map
#define OUT_X_OFF   0
#define OUT_O_OFF   524288
#define OUT_CM_OFF  540672

// compare-exchange (ascending)
#define CE(x, y) { float ce_lo = fminf(x, y); y = fmaxf(x, y); x = ce_lo; }

__device__ __forceinline__ float bilin32(const float* src, int b, int y, int x) {
    float sy = 0.5f * y - 0.25f;
    float sx = 0.5f * x - 0.25f;
    float fy0 = floorf(sy), fx0 = floorf(sx);
    int y0 = (int)fy0, x0 = (int)fx0;
    float fy = sy - fy0, fx = sx - fx0;
    int y0c = min(max(y0, 0), 31), y1c = min(max(y0 + 1, 0), 31);
    int x0c = min(max(x0, 0), 31), x1c = min(max(x0 + 1, 0), 31);
    const float* p = src + b * 1024;
    float v00 = p[y0c * 32 + x0c], v01 = p[y0c * 32 + x1c];
    float v10 = p[y1c * 32 + x0c], v11 = p[y1c * 32 + x1c];
    float v0 = v00 + fx * (v01 - v00);
    float v1 = v10 + fx * (v11 - v10);
    return v0 + fy * (v1 - v0);
}

// K0: pos embedding projected through wq/wk, per coordinate (exact).
__global__ void k0_posproj(const float* __restrict__ wq, const float* __restrict__ wk,
                           float* __restrict__ pp) {
    int t = threadIdx.x;  // coordinate 0..63
    float coord = (float)(t + 1);
    float qy[4] = {0,0,0,0}, qx[4] = {0,0,0,0}, ky[4] = {0,0,0,0}, kx[4] = {0,0,0,0};
    for (int c = 0; c < 32; ++c) {
        float e = (2.0f * (float)(c / 2)) / 32.0f;
        float dim = powf(10000.0f, e);
        float ang = coord / dim;
        float pr = (c & 1) ? cosf(ang) : sinf(ang);
        #pragma unroll
        for (int m = 0; m < 4; ++m) {
            qy[m] += wq[m * 64 + c] * pr;
            qx[m] += wq[m * 64 + 32 + c] * pr;
            ky[m] += wk[m * 64 + c] * pr;
            kx[m] += wk[m * 64 + 32 + c] * pr;
        }
    }
    #pragma unroll
    for (int m = 0; m < 4; ++m) {
        pp[0 * 256 + m * 64 + t] = qy[m];
        pp[1 * 256 + m * 64 + t] = qx[m];
        pp[2 * 256 + m * 64 + t] = ky[m];
        pp[3 * 256 + m * 64 + t] = kx[m];
    }
}

// K1: Q/K projections, channel-split 4x16 + LDS reduce. grid = B*N/64 = 256
__global__ void k1_qk(const float* __restrict__ fq, const float* __restrict__ fk,
                      const float* __restrict__ wq, const float* __restrict__ wk,
                      const float* __restrict__ pp,
                      float* __restrict__ Q4, float* __restrict__ K4) {
    __shared__ float wqs[256], wks[256];
    __shared__ float red[256][9];
    int tid = threadIdx.x;
    wqs[tid] = wq[tid];
    wks[tid] = wk[tid];
    __syncthreads();
    int qi = tid & 63, g = tid >> 6;
    int gid = blockIdx.x * 64 + qi;
    int b = gid >> 12, hw = gid & 4095;
    const float* fqb = fq + (size_t)b * CIN * NN + hw;
    const float* fkb = fk + (size_t)b * CIN * NN + hw;
    float aq[4] = {0,0,0,0}, ak[4] = {0,0,0,0};
    int c0 = g * 16;
    #pragma unroll 4
    for (int c = c0; c < c0 + 16; ++c) {
        float vq = fqb[c * NN];
        float vk = fkb[c * NN];
        #pragma unroll
        for (int m = 0; m < 4; ++m) {
            aq[m] += wqs[m * 64 + c] * vq;
            ak[m] += wks[m * 64 + c] * vk;
        }
    }
    #pragma unroll
    for (int m = 0; m < 4; ++m) { red[tid][m] = aq[m]; red[tid][4 + m] = ak[m]; }
    __syncthreads();
    if (tid < 64) {
        int y = hw >> 6, x = hw & 63;
        float q4[4], k4[4];
        #pragma unroll
        for (int m = 0; m < 4; ++m) {
            q4[m] = LOG2E * (red[tid][m] + red[tid + 64][m] + red[tid + 128][m] + red[tid + 192][m]
                  + pp[0 * 256 + m * 64 + y] + pp[1 * 256 + m * 64 + x]);
            k4[m] = red[tid][4 + m] + red[tid + 64][4 + m] + red[tid + 128][4 + m] + red[tid + 192][4 + m]
                  + pp[2 * 256 + m * 64 + y] + pp[3 * 256 + m * 64 + x];
        }
        ((float4*)Q4)[gid] = make_float4(q4[0], q4[1], q4[2], q4[3]);
        ((float4*)K4)[gid] = make_float4(k4[0], k4[1], k4[2], k4[3]);
    }
}

// K2a: per-(b, q-chunk of 128) column sum of 2^(q'.k). grid = B*NQCH*8 = 1024
__global__ void k2a_colstats(const float* __restrict__ Q4, const float* __restrict__ K4,
                             float* __restrict__ cpsum) {
    __shared__ float4 Qs[128];
    int blk = blockIdx.x;
    int kblk = blk & 7;   blk >>= 3;
    int qch  = blk & 31;  blk >>= 5;
    int b    = blk;
    int tid = threadIdx.x;
    if (tid < 128)
        Qs[tid] = ((const float4*)Q4)[b * NN + qch * 128 + tid];
    __syncthreads();
    int k0 = kblk * 512 + tid;
    float4 kva = ((const float4*)K4)[b * NN + k0];
    float4 kvb = ((const float4*)K4)[b * NN + k0 + 256];
    float sa = 0.0f, sb = 0.0f;
    #pragma unroll 8
    for (int i = 0; i < 128; ++i) {
        float4 q = Qs[i];
        float da = fmaf(q.x, kva.x, fmaf(q.y, kva.y, fmaf(q.z, kva.z, q.w * kva.w)));
        float db = fmaf(q.x, kvb.x, fmaf(q.y, kvb.y, fmaf(q.z, kvb.z, q.w * kvb.w)));
        sa += exp2f(da);
        sb += exp2f(db);
    }
    cpsum[(b * NQCH + qch) * NN + k0] = sa;
    cpsum[(b * NQCH + qch) * NN + k0 + 256] = sb;
}

// K2b: merge chunk sums -> c'[b][k] = LOG2E*(m_k_r - 1) - log2(colsum)
__global__ void k2b_cmerge(const float* __restrict__ cpsum,
                           const float* __restrict__ m_k, float* __restrict__ cvals) {
    int gid = blockIdx.x * 256 + threadIdx.x;  // B*N
    int b = gid >> 12, k = gid & 4095;
    float S = 0.0f;
    #pragma unroll
    for (int j = 0; j < NQCH; ++j) S += cpsum[(b * NQCH + j) * NN + k];
    float mk = bilin32(m_k, b, k >> 6, k & 63);
    cvals[gid] = LOG2E * (mk - 1.0f) - log2f(S);
}

// K3a: lane-per-query chunk scan, 8 waves/block, 2 insert chains per lane.
// Wave half h scans keys [256h, 256h+256) of the staged 512-key chunk as two
// independent 128-key chains (2x ILP on the dep-chain). Exact merges:
// bitonic max-merge (sorted8 x sorted8 -> top8) + 12-CE bitonic sort; halves
// merge via LDS. One exact top-8 per (query, chunk) -> T8. grid = B*16*8.
__global__ __launch_bounds__(512) void k3a_scan(
        const float* __restrict__ Q4, const float* __restrict__ K4,
        const float* __restrict__ cvals, float* __restrict__ t8) {
    __shared__ float4 kvs[512];        // 8 KB
    __shared__ float  cvs[512];        // 2 KB
    __shared__ float  sbuf[4][64][9];  // 9 KB (pad 9: bank-spread)
    int blk = blockIdx.x;
    int kc = blk & 7;   blk >>= 3;
    int g2 = blk & 15;  blk >>= 4;
    int b  = blk;
    int tid = threadIdx.x;
    int wave = tid >> 6, lane = tid & 63;
    int half = wave >> 2, wsub = wave & 3;

    const float4* Kb = (const float4*)K4 + b * NN + kc * 512;
    const float* cb = cvals + b * NN + kc * 512;
    if (tid < 512) { kvs[tid] = Kb[tid]; cvs[tid] = cb[tid]; }
    __syncthreads();

    int qrow = (g2 * 4 + wsub) * 64 + lane;
    float4 qv = ((const float4*)Q4)[b * NN + qrow];

    // two independent chains over disjoint 128-key ranges (ascending t-buffers)
    float a0=-1e30f,a1=-1e30f,a2=-1e30f,a3=-1e30f,a4=-1e30f,a5=-1e30f,a6=-1e30f,a7=-1e30f;
    float c0=-1e30f,c1=-1e30f,c2=-1e30f,c3=-1e30f,c4=-1e30f,c5=-1e30f,c6=-1e30f,c7=-1e30f;
    int base = half * 256;
    #pragma unroll 2
    for (int i = 0; i < 128; ++i) {
        float4 ka = kvs[base + i];
        float sa = fmaf(qv.x, ka.x, fmaf(qv.y, ka.y,
                   fmaf(qv.z, ka.z, fmaf(qv.w, ka.w, cvs[base + i]))));
        float4 kb = kvs[base + 128 + i];
        float sb = fmaf(qv.x, kb.x, fmaf(qv.y, kb.y,
                   fmaf(qv.z, kb.z, fmaf(qv.w, kb.w, cvs[base + 128 + i]))));
        if (sa > a0) {
            float z = fmaxf(a0, sa);
            a0 = fminf(z, a1); z = fmaxf(z, a1);
            a1 = fminf(z, a2); z = fmaxf(z, a2);
            a2 = fminf(z, a3); z = fmaxf(z, a3);
            a3 = fminf(z, a4); z = fmaxf(z, a4);
            a4 = fminf(z, a5); z = fmaxf(z, a5);
            a5 = fminf(z, a6); z = fmaxf(z, a6);
            a6 = fminf(z, a7); a7 = fmaxf(z, a7);
        }
        if (sb > c0) {
            float z = fmaxf(c0, sb);
            c0 = fminf(z, c1); z = fmaxf(z, c1);
            c1 = fminf(z, c2); z = fmaxf(z, c2);
            c2 = fminf(z, c3); z = fmaxf(z, c3);
            c3 = fminf(z, c4); z = fmaxf(z, c4);
            c4 = fminf(z, c5); z = fmaxf(z, c5);
            c5 = fminf(z, c6); z = fmaxf(z, c6);
            c6 = fminf(z, c7); c7 = fmaxf(z, c7);
        }
    }
    // merge chains: r_i = max(a_i, c_{7-i}) -> valley-bitonic top-8 of 256
    float r0 = fmaxf(a0, c7), r1 = fmaxf(a1, c6), r2 = fmaxf(a2, c5), r3 = fmaxf(a3, c4);
    float r4 = fmaxf(a4, c3), r5 = fmaxf(a5, c2), r6 = fmaxf(a6, c1), r7 = fmaxf(a7, c0);
    // bitonic sort (8, ascending): stages 4,2,1
    CE(r0, r4); CE(r1, r5); CE(r2, r6); CE(r3, r7);
    CE(r0, r2); CE(r1, r3); CE(r4, r6); CE(r5, r7);
    CE(r0, r1); CE(r2, r3); CE(r4, r5); CE(r6, r7);

    if (half == 1) {
        float* sb_ = &sbuf[wsub][lane][0];
        sb_[0] = r0; sb_[1] = r1; sb_[2] = r2; sb_[3] = r3;
        sb_[4] = r4; sb_[5] = r5; sb_[6] = r6; sb_[7] = r7;
    }
    __syncthreads();
    if (half == 0) {
        const float* sb_ = &sbuf[wsub][lane][0];
        float f0 = fmaxf(r0, sb_[7]);
        float f1 = fmaxf(r1, sb_[6]);
        float f2 = fmaxf(r2, sb_[5]);
        float f3 = fmaxf(r3, sb_[4]);
        float f4 = fmaxf(r4, sb_[3]);
        float f5 = fmaxf(r5, sb_[2]);
        float f6 = fmaxf(r6, sb_[1]);
        float f7 = fmaxf(r7, sb_[0]);
        float* o = t8 + ((size_t)(b * NN + qrow)) * 64 + kc * 8;
        o[0] = f0; o[1] = f1; o[2] = f2; o[3] = f3;
        o[4] = f4; o[5] = f5; o[6] = f6; o[7] = f7;
    }
}

// K3b: merge 8 chunk-top8s (64 candidates) -> global top-8 -> cm/rmap.
__global__ void k3b_merge(const float* __restrict__ t8, const float* __restrict__ mapin,
                          float* __restrict__ rmap, float* __restrict__ cmapf,
                          float* __restrict__ outp) {
    int tid = threadIdx.x;
    int qid = blockIdx.x * 4 + (tid >> 6);   // 0 .. B*N-1
    int lane = tid & 63;
    float v = t8[(size_t)qid * 64 + lane];
    float sm = 0.0f;
    #pragma unroll
    for (int r = 0; r < 8; ++r) {
        float m = v;
        int ln = lane;
        #pragma unroll
        for (int off = 32; off >= 1; off >>= 1) {
            float om = __shfl_xor(m, off);
            int ol = __shfl_xor(ln, off);
            if (om > m || (om == m && ol < ln)) { m = om; ln = ol; }
        }
        sm += exp2f(m);
        if (lane == ln) v = -1e30f;
    }
    if (lane == 0) {
        float cmv = sm * 0.125f;
        int b = qid >> 12, hw = qid & 4095;
        float mr = bilin32(mapin, b, hw >> 6, hw & 63);
        float cm = cmv * mr + mr;
        float rm = 1.0f / (1.0f + __expf(cm));
        rmap[qid] = rm;
        cmapf[qid] = cm;
        outp[OUT_CM_OFF + qid] = cm;
    }
}

// K4: x1 = conv1x1(rmap*f, w_in) + b_in. og-split 8 -> grid 512
__global__ void k4_conv1(const float* __restrict__ f, const float* __restrict__ rmap,
                         const float* __restrict__ w_in, const float* __restrict__ b_in,
                         float* __restrict__ xout) {
    __shared__ float ws_[1024];
    __shared__ float bs[32];
    int tid = threadIdx.x;
    for (int i = tid; i < 1024; i += 256) ws_[i] = w_in[i];
    if (tid < 32) bs[tid] = b_in[tid];
    __syncthreads();
    int gid = blockIdx.x * 256 + tid;      // b(2b) og(3b) hw(12b)
    int hw = gid & 4095;
    int og = (gid >> 12) & 7;
    int b  = gid >> 15;
    float rm = rmap[b * NN + hw];
    float acc[4];
    #pragma unroll
    for (int j = 0; j < 4; ++j) acc[j] = bs[og * 4 + j];
    const float* fb = f + (size_t)b * CH * NN + hw;
    for (int i = 0; i < 32; ++i) {
        float v = fb[i * NN] * rm;
        #pragma unroll
        for (int j = 0; j < 4; ++j) acc[j] += ws_[(og * 4 + j) * 32 + i] * v;
    }
    float* xo = xout + (size_t)b * CH * NN + (og * 4) * NN + hw;
    #pragma unroll
    for (int j = 0; j < 4; ++j) xo[j * NN] = acc[j];
}

// K5: 3x3 conv 32->32 (+bias, relu). og-split 8 -> grid = b*ty*tx*og = 512
__global__ void k5_conv3(const float* __restrict__ xin, const float* __restrict__ w,
                         const float* __restrict__ bias, float* __restrict__ xout,
                         float* __restrict__ outx) {
    __shared__ float tile[32][324];   // 18x18 per channel
    __shared__ float wsm[1152];       // 4 o x 32 i x 9
    __shared__ float bsm[4];
    int blk = blockIdx.x;
    int og = blk & 7;  blk >>= 3;
    int tx = blk & 3;  blk >>= 2;
    int ty = blk & 3;  blk >>= 2;
    int b  = blk;
    int tid = threadIdx.x;
    for (int i = tid; i < 1152; i += 256) wsm[i] = w[og * 1152 + i];
    if (tid < 4) bsm[tid] = bias[og * 4 + tid];
    int y0 = ty * 16 - 1, x0 = tx * 16 - 1;
    for (int i = tid; i < 32 * 324; i += 256) {
        int c = i / 324, r = i % 324;
        int yy = r / 18, xx = r % 18;
        int gy = y0 + yy, gx = x0 + xx;
        float v = 0.0f;
        if (gy >= 0 && gy < 64 && gx >= 0 && gx < 64)
            v = xin[((size_t)b * CH + c) * NN + gy * 64 + gx];
        tile[c][r] = v;
    }
    __syncthreads();
    int py = tid >> 4, px = tid & 15;
    float acc[4];
    #pragma unroll
    for (int j = 0; j < 4; ++j) acc[j] = bsm[j];
    for (int i = 0; i < 32; ++i) {
        const float* tr = &tile[i][py * 18 + px];
        float v00 = tr[0],  v01 = tr[1],  v02 = tr[2];
        float v10 = tr[18], v11 = tr[19], v12 = tr[20];
        float v20 = tr[36], v21 = tr[37], v22 = tr[38];
        #pragma unroll
        for (int j = 0; j < 4; ++j) {
            const float* wj = &wsm[j * 288 + i * 9];
            acc[j] += v00 * wj[0] + v01 * wj[1] + v02 * wj[2]
                    + v10 * wj[3] + v11 * wj[4] + v12 * wj[5]
                    + v20 * wj[6] + v21 * wj[7] + v22 * wj[8];
        }
    }
    size_t base = (size_t)b * CH * NN + (size_t)(og * 4) * NN
                + (ty * 16 + py) * 64 + tx * 16 + px;
    #pragma unroll
    for (int j = 0; j < 4; ++j) {
        float r_ = fmaxf(acc[j], 0.0f);
        xout[base + j * NN] = r_;
        if (outx) outx[base + j * NN] = r_;
    }
}

// K6: final 3x3 conv 32->1 + b_out + corrected_map. channel-split 4x8, grid 256
__global__ void k6_convout(const float* __restrict__ xin, const float* __restrict__ w_out,
                           const float* __restrict__ b_out, const float* __restrict__ cmapf,
                           float* __restrict__ outp) {
    __shared__ float wsm[288];
    __shared__ float red[256];
    int tid = threadIdx.x;
    for (int i = tid; i < 288; i += 256) wsm[i] = w_out[i];
    int pxi = tid & 63, g = tid >> 6;
    int gid = blockIdx.x * 64 + pxi;   // B*N over 256 blocks
    int b = gid >> 12, hw = gid & 4095;
    int y = hw >> 6, x = hw & 63;
    __syncthreads();
    float acc = 0.0f;
    int c0 = g * 8;
    for (int i = c0; i < c0 + 8; ++i) {
        const float* xi = xin + ((size_t)b * CH + i) * NN;
        #pragma unroll
        for (int ky = 0; ky < 3; ++ky) {
            int gy = y + ky - 1;
            if (gy < 0 || gy > 63) continue;
            #pragma unroll
            for (int kx = 0; kx < 3; ++kx) {
                int gx = x + kx - 1;
                if (gx < 0 || gx > 63) continue;
                acc += xi[gy * 64 + gx] * wsm[i * 9 + ky * 3 + kx];
            }
        }
    }
    red[tid] = acc;
    __syncthreads();
    if (tid < 64) {
        float a = red[tid] + red[tid + 64] + red[tid + 128] + red[tid + 192]
                + b_out[0] + cmapf[gid];
        outp[OUT_O_OFF + gid] = a;
    }
}

extern "C" void kernel_launch(void* const* d_in, const int* in_sizes, int n_in,
                              void* d_out, int out_size, void* d_ws, size_t ws_size,
                              hipStream_t stream) {
    const float* f     = (const float*)d_in[0];
    const float* mapin = (const float*)d_in[1];
    const float* f_q   = (const float*)d_in[2];
    const float* f_k   = (const float*)d_in[3];
    const float* m_k   = (const float*)d_in[4];
    const float* wq    = (const float*)d_in[5];
    const float* wk    = (const float*)d_in[6];
    const float* w_in  = (const float*)d_in[7];
    const float* b_in  = (const float*)d_in[8];
    const float* w_mid = (const float*)d_in[9];
    const float* b_mid = (const float*)d_in[10];
    const float* w_out = (const float*)d_in[11];
    const float* b_out = (const float*)d_in[12];
    float* outp = (float*)d_out;
    float* ws = (float*)d_ws;

    float* PP    = ws + PP_OFF;
    float* Q4    = ws + Q4_OFF;
    float* K4    = ws + K4_OFF;
    float* CV    = ws + CV_OFF;
    float* CPSUM = ws + CPSUM_OFF;
    float* RMAP  = ws + RMAP_OFF;
    float* CMAPF = ws + CMAPF_OFF;
    float* T8    = ws + T8_OFF;
    float* XA    = ws + XA_OFF;
    float* XB    = ws + XB_OFF;

    k0_posproj<<<1, 64, 0, stream>>>(wq, wk, PP);
    k1_qk<<<256, 256, 0, stream>>>(f_q, f_k, wq, wk, PP, Q4, K4);
    k2a_colstats<<<BB * NQCH * 8, 256, 0, stream>>>(Q4, K4, CPSUM);
    k2b_cmerge<<<64, 256, 0, stream>>>(CPSUM, m_k, CV);
    k3a_scan<<<BB * 16 * 8, 512, 0, stream>>>(Q4, K4, CV, T8);
    k3b_merge<<<BB * NN / 4, 256, 0, stream>>>(T8, mapin, RMAP, CMAPF, outp);
    k4_conv1<<<512, 256, 0, stream>>>(f, RMAP, w_in, b_in, XA);
    k5_conv3<<<512, 256, 0, stream>>>(XA, w_mid + 0 * 9216, b_mid + 0 * 32, XB, (float*)0);
    k5_conv3<<<512, 256, 0, stream>>>(XB, w_mid + 1 * 9216, b_mid + 1 * 32, XA, (float*)0);
    k5_conv3<<<512, 256, 0, stream>>>(XA, w_mid + 2 * 9216, b_mid + 2 * 32, XB, outp + OUT_X_OFF);
    k6_convout<<<256, 256, 0, stream>>>(XB, w_out, b_out, CMAPF, outp);
}

// Round 11
// 223.460 us; speedup vs baseline: 1.0537x; 1.0261x over previous
//
#include <hip/hip_runtime.h>
#include <hip/hip_bf16.h>
#include <math.h>

// Problem constants
#define BB 4
#define CIN 64
#define CH 32
#define HH 64
#define WW 64
#define NN 4096           // H*W
#define MCH 4
#define NQCH 32           // q-chunks for column stats (chunk = 128 queries)
#define LOG2E 1.4426950408889634f

// ws layout (floats). Total 1,229,824 floats = 4.69 MiB (proven size).
#define PP_OFF     0          // 1024
#define Q4_OFF     1024       // 65536  (Q pre-scaled by LOG2E)
#define K4_OFF     66560      // 65536
#define CV_OFF     132096     // 16384  (c' in log2 domain)
#define CPSUM_OFF  672768     // 524288 (dead after k2b)
#define RMAP_OFF   148480     // 16384
#define CMAPF_OFF  164864     // 16384
#define T8_OFF     181248     // 1048576 (XA+XB region; dead after k3b)
#define XA_OFF     181248     // 524288
#define XB_OFF     705536     // 524288

// out layout (FLOAT32 elements): x | out | corrected_map
#define OUT_X_OFF   0
#define OUT_O_OFF   524288
#define OUT_CM_OFF  540672

// compare-exchange (ascending)
#define CE(x, y) { float ce_lo = fminf(x, y); y = fmaxf(x, y); x = ce_lo; }

__device__ __forceinline__ float bilin32(const float* src, int b, int y, int x) {
    float sy = 0.5f * y - 0.25f;
    float sx = 0.5f * x - 0.25f;
    float fy0 = floorf(sy), fx0 = floorf(sx);
    int y0 = (int)fy0, x0 = (int)fx0;
    float fy = sy - fy0, fx = sx - fx0;
    int y0c = min(max(y0, 0), 31), y1c = min(max(y0 + 1, 0), 31);
    int x0c = min(max(x0, 0), 31), x1c = min(max(x0 + 1, 0), 31);
    const float* p = src + b * 1024;
    float v00 = p[y0c * 32 + x0c], v01 = p[y0c * 32 + x1c];
    float v10 = p[y1c * 32 + x0c], v11 = p[y1c * 32 + x1c];
    float v0 = v00 + fx * (v01 - v00);
    float v1 = v10 + fx * (v11 - v10);
    return v0 + fy * (v1 - v0);
}

// K0: pos embedding projected through wq/wk, per coordinate (exact).
__global__ void k0_posproj(const float* __restrict__ wq, const float* __restrict__ wk,
                           float* __restrict__ pp) {
    int t = threadIdx.x;  // coordinate 0..63
    float coord = (float)(t + 1);
    float qy[4] = {0,0,0,0}, qx[4] = {0,0,0,0}, ky[4] = {0,0,0,0}, kx[4] = {0,0,0,0};
    for (int c = 0; c < 32; ++c) {
        float e = (2.0f * (float)(c / 2)) / 32.0f;
        float dim = powf(10000.0f, e);
        float ang = coord / dim;
        float pr = (c & 1) ? cosf(ang) : sinf(ang);
        #pragma unroll
        for (int m = 0; m < 4; ++m) {
            qy[m] += wq[m * 64 + c] * pr;
            qx[m] += wq[m * 64 + 32 + c] * pr;
            ky[m] += wk[m * 64 + c] * pr;
            kx[m] += wk[m * 64 + 32 + c] * pr;
        }
    }
    #pragma unroll
    for (int m = 0; m < 4; ++m) {
        pp[0 * 256 + m * 64 + t] = qy[m];
        pp[1 * 256 + m * 64 + t] = qx[m];
        pp[2 * 256 + m * 64 + t] = ky[m];
        pp[3 * 256 + m * 64 + t] = kx[m];
    }
}

// K1: Q/K projections, channel-split 8x8 + LDS reduce. 512-thread blocks,
// grid = B*N/64 = 256 (8 waves/block -> 2 waves/SIMD).
__global__ __launch_bounds__(512) void k1_qk(
        const float* __restrict__ fq, const float* __restrict__ fk,
        const float* __restrict__ wq, const float* __restrict__ wk,
        const float* __restrict__ pp,
        float* __restrict__ Q4, float* __restrict__ K4) {
    __shared__ float wqs[256], wks[256];
    __shared__ float red[512][9];
    int tid = threadIdx.x;
    if (tid < 256) { wqs[tid] = wq[tid]; wks[tid] = wk[tid]; }
    __syncthreads();
    int qi = tid & 63, g = tid >> 6;      // g = 0..7 channel group
    int gid = blockIdx.x * 64 + qi;
    int b = gid >> 12, hw = gid & 4095;
    const float* fqb = fq + (size_t)b * CIN * NN + hw;
    const float* fkb = fk + (size_t)b * CIN * NN + hw;
    float aq[4] = {0,0,0,0}, ak[4] = {0,0,0,0};
    int c0 = g * 8;
    #pragma unroll
    for (int c = c0; c < c0 + 8; ++c) {
        float vq = fqb[c * NN];
        float vk = fkb[c * NN];
        #pragma unroll
        for (int m = 0; m < 4; ++m) {
            aq[m] += wqs[m * 64 + c] * vq;
            ak[m] += wks[m * 64 + c] * vk;
        }
    }
    #pragma unroll
    for (int m = 0; m < 4; ++m) { red[tid][m] = aq[m]; red[tid][4 + m] = ak[m]; }
    __syncthreads();
    if (tid < 64) {
        int y = hw >> 6, x = hw & 63;
        float q4[4], k4[4];
        #pragma unroll
        for (int m = 0; m < 4; ++m) {
            float sq = 0.0f, sk = 0.0f;
            #pragma unroll
            for (int j = 0; j < 8; ++j) {
                sq += red[tid + 64 * j][m];
                sk += red[tid + 64 * j][4 + m];
            }
            q4[m] = LOG2E * (sq + pp[0 * 256 + m * 64 + y] + pp[1 * 256 + m * 64 + x]);
            k4[m] = sk + pp[2 * 256 + m * 64 + y] + pp[3 * 256 + m * 64 + x];
        }
        ((float4*)Q4)[gid] = make_float4(q4[0], q4[1], q4[2], q4[3]);
        ((float4*)K4)[gid] = make_float4(k4[0], k4[1], k4[2], k4[3]);
    }
}

// K2a: per-(b, q-chunk of 128) column sum of 2^(q'.k). Queries read via
// UNIFORM global address (scalar-cache broadcast; no LDS). grid = B*32*8.
__global__ void k2a_colstats(const float* __restrict__ Q4, const float* __restrict__ K4,
                             float* __restrict__ cpsum) {
    int blk = blockIdx.x;
    int kblk = blk & 7;   blk >>= 3;
    int qch  = blk & 31;  blk >>= 5;
    int b    = blk;
    int tid = threadIdx.x;
    const float4* Qg = (const float4*)Q4 + b * NN + qch * 128;  // uniform base
    int k0 = kblk * 512 + tid;
    float4 kva = ((const float4*)K4)[b * NN + k0];
    float4 kvb = ((const float4*)K4)[b * NN + k0 + 256];
    float sa = 0.0f, sb = 0.0f;
    #pragma unroll 8
    for (int i = 0; i < 128; ++i) {
        float4 q = Qg[i];   // uniform -> s_load broadcast
        float da = fmaf(q.x, kva.x, fmaf(q.y, kva.y, fmaf(q.z, kva.z, q.w * kva.w)));
        float db = fmaf(q.x, kvb.x, fmaf(q.y, kvb.y, fmaf(q.z, kvb.z, q.w * kvb.w)));
        sa += exp2f(da);
        sb += exp2f(db);
    }
    cpsum[(b * NQCH + qch) * NN + k0] = sa;
    cpsum[(b * NQCH + qch) * NN + k0 + 256] = sb;
}

// K2b: merge chunk sums -> c'[b][k] = LOG2E*(m_k_r - 1) - log2(colsum)
__global__ void k2b_cmerge(const float* __restrict__ cpsum,
                           const float* __restrict__ m_k, float* __restrict__ cvals) {
    int gid = blockIdx.x * 256 + threadIdx.x;  // B*N
    int b = gid >> 12, k = gid & 4095;
    float S = 0.0f;
    #pragma unroll
    for (int j = 0; j < NQCH; ++j) S += cpsum[(b * NQCH + j) * NN + k];
    float mk = bilin32(m_k, b, k >> 6, k & 63);
    cvals[gid] = LOG2E * (mk - 1.0f) - log2f(S);
}

// K3a: lane-per-query chunk scan v3.
// Keys read via UNIFORM global addresses -> scalar loads (SGPR broadcast):
// zero LDS, zero vector-memory in the hot loop. Inner loop processes batches
// of 8 keys: 8 independent dots, batch-max guard, Batcher sort-8 (19 CE),
// bitonic max-merge into running sorted top-8 (8 fmax + 12 CE).
// grid = B*16*8 = 512 blocks x 256 threads (4 waves; wave = 64 queries).
__global__ __launch_bounds__(256) void k3a_scan(
        const float* __restrict__ Q4, const float* __restrict__ K4,
        const float* __restrict__ cvals, float* __restrict__ t8) {
    int blk = blockIdx.x;
    int kc = blk & 7;   blk >>= 3;
    int g4 = blk & 15;  blk >>= 4;
    int b  = blk;
    int tid = threadIdx.x;
    int wave = tid >> 6, lane = tid & 63;
    int qrow = (g4 * 4 + wave) * 64 + lane;
    float4 qv = ((const float4*)Q4)[b * NN + qrow];
    const float4* Kb = (const float4*)K4 + b * NN + kc * 512;   // uniform base
    const float* cb = cvals + b * NN + kc * 512;                // uniform base

    float t0=-1e30f,t1=-1e30f,t2=-1e30f,t3=-1e30f;
    float t4=-1e30f,t5=-1e30f,t6=-1e30f,t7=-1e30f;   // ascending; t0 = 8th

    #pragma unroll 2
    for (int i0 = 0; i0 < 512; i0 += 8) {
        float4 k0 = Kb[i0 + 0]; float4 k1 = Kb[i0 + 1];
        float4 k2 = Kb[i0 + 2]; float4 k3 = Kb[i0 + 3];
        float4 k4 = Kb[i0 + 4]; float4 k5 = Kb[i0 + 5];
        float4 k6 = Kb[i0 + 6]; float4 k7 = Kb[i0 + 7];
        float s0 = fmaf(qv.x,k0.x, fmaf(qv.y,k0.y, fmaf(qv.z,k0.z, qv.w*k0.w))) + cb[i0+0];
        float s1 = fmaf(qv.x,k1.x, fmaf(qv.y,k1.y, fmaf(qv.z,k1.z, qv.w*k1.w))) + cb[i0+1];
        float s2 = fmaf(qv.x,k2.x, fmaf(qv.y,k2.y, fmaf(qv.z,k2.z, qv.w*k2.w))) + cb[i0+2];
        float s3 = fmaf(qv.x,k3.x, fmaf(qv.y,k3.y, fmaf(qv.z,k3.z, qv.w*k3.w))) + cb[i0+3];
        float s4 = fmaf(qv.x,k4.x, fmaf(qv.y,k4.y, fmaf(qv.z,k4.z, qv.w*k4.w))) + cb[i0+4];
        float s5 = fmaf(qv.x,k5.x, fmaf(qv.y,k5.y, fmaf(qv.z,k5.z, qv.w*k5.w))) + cb[i0+5];
        float s6 = fmaf(qv.x,k6.x, fmaf(qv.y,k6.y, fmaf(qv.z,k6.z, qv.w*k6.w))) + cb[i0+6];
        float s7 = fmaf(qv.x,k7.x, fmaf(qv.y,k7.y, fmaf(qv.z,k7.z, qv.w*k7.w))) + cb[i0+7];
        float bm = fmaxf(fmaxf(fmaxf(s0,s1), fmaxf(s2,s3)),
                         fmaxf(fmaxf(s4,s5), fmaxf(s6,s7)));
        if (bm > t0) {
            // Batcher odd-even mergesort, 8 elems ascending (19 CE)
            CE(s0,s1); CE(s2,s3); CE(s4,s5); CE(s6,s7);
            CE(s0,s2); CE(s1,s3); CE(s4,s6); CE(s5,s7);
            CE(s1,s2); CE(s5,s6);
            CE(s0,s4); CE(s1,s5); CE(s2,s6); CE(s3,s7);
            CE(s2,s4); CE(s3,s5);
            CE(s1,s2); CE(s3,s4); CE(s5,s6);
            // bitonic max-merge: top-8 of {t} u {s} (both ascending)
            t0 = fmaxf(t0, s7); t1 = fmaxf(t1, s6); t2 = fmaxf(t2, s5); t3 = fmaxf(t3, s4);
            t4 = fmaxf(t4, s3); t5 = fmaxf(t5, s2); t6 = fmaxf(t6, s1); t7 = fmaxf(t7, s0);
            // result is bitonic -> 12-CE bitonic sort (ascending)
            CE(t0,t4); CE(t1,t5); CE(t2,t6); CE(t3,t7);
            CE(t0,t2); CE(t1,t3); CE(t4,t6); CE(t5,t7);
            CE(t0,t1); CE(t2,t3); CE(t4,t5); CE(t6,t7);
        }
    }
    float* o = t8 + ((size_t)(b * NN + qrow)) * 64 + kc * 8;
    o[0] = t0; o[1] = t1; o[2] = t2; o[3] = t3;
    o[4] = t4; o[5] = t5; o[6] = t6; o[7] = t7;
}

// K3b: merge 8 chunk-top8s (64 candidates) -> global top-8 -> cm/rmap.
__global__ void k3b_merge(const float* __restrict__ t8, const float* __restrict__ mapin,
                          float* __restrict__ rmap, float* __restrict__ cmapf,
                          float* __restrict__ outp) {
    int tid = threadIdx.x;
    int qid = blockIdx.x * 4 + (tid >> 6);   // 0 .. B*N-1
    int lane = tid & 63;
    float v = t8[(size_t)qid * 64 + lane];
    float sm = 0.0f;
    #pragma unroll
    for (int r = 0; r < 8; ++r) {
        float m = v;
        int ln = lane;
        #pragma unroll
        for (int off = 32; off >= 1; off >>= 1) {
            float om = __shfl_xor(m, off);
            int ol = __shfl_xor(ln, off);
            if (om > m || (om == m && ol < ln)) { m = om; ln = ol; }
        }
        sm += exp2f(m);
        if (lane == ln) v = -1e30f;
    }
    if (lane == 0) {
        float cmv = sm * 0.125f;
        int b = qid >> 12, hw = qid & 4095;
        float mr = bilin32(mapin, b, hw >> 6, hw & 63);
        float cm = cmv * mr + mr;
        float rm = 1.0f / (1.0f + __expf(cm));
        rmap[qid] = rm;
        cmapf[qid] = cm;
        outp[OUT_CM_OFF + qid] = cm;
    }
}

// K4: x1 = conv1x1(rmap*f, w_in) + b_in. og-split 8 -> grid 512
__global__ void k4_conv1(const float* __restrict__ f, const float* __restrict__ rmap,
                         const float* __restrict__ w_in, const float* __restrict__ b_in,
                         float* __restrict__ xout) {
    __shared__ float ws_[1024];
    __shared__ float bs[32];
    int tid = threadIdx.x;
    for (int i = tid; i < 1024; i += 256) ws_[i] = w_in[i];
    if (tid < 32) bs[tid] = b_in[tid];
    __syncthreads();
    int gid = blockIdx.x * 256 + tid;      // b(2b) og(3b) hw(12b)
    int hw = gid & 4095;
    int og = (gid >> 12) & 7;
    int b  = gid >> 15;
    float rm = rmap[b * NN + hw];
    float acc[4];
    #pragma unroll
    for (int j = 0; j < 4; ++j) acc[j] = bs[og * 4 + j];
    const float* fb = f + (size_t)b * CH * NN + hw;
    for (int i = 0; i < 32; ++i) {
        float v = fb[i * NN] * rm;
        #pragma unroll
        for (int j = 0; j < 4; ++j) acc[j] += ws_[(og * 4 + j) * 32 + i] * v;
    }
    float* xo = xout + (size_t)b * CH * NN + (og * 4) * NN + hw;
    #pragma unroll
    for (int j = 0; j < 4; ++j) xo[j * NN] = acc[j];
}

// K5: 3x3 conv 32->32 (+bias, relu). og-split 8 -> grid = b*ty*tx*og = 512
__global__ void k5_conv3(const float* __restrict__ xin, const float* __restrict__ w,
                         const float* __restrict__ bias, float* __restrict__ xout,
                         float* __restrict__ outx) {
    __shared__ float tile[32][324];   // 18x18 per channel
    __shared__ float wsm[1152];       // 4 o x 32 i x 9
    __shared__ float bsm[4];
    int blk = blockIdx.x;
    int og = blk & 7;  blk >>= 3;
    int tx = blk & 3;  blk >>= 2;
    int ty = blk & 3;  blk >>= 2;
    int b  = blk;
    int tid = threadIdx.x;
    for (int i = tid; i < 1152; i += 256) wsm[i] = w[og * 1152 + i];
    if (tid < 4) bsm[tid] = bias[og * 4 + tid];
    int y0 = ty * 16 - 1, x0 = tx * 16 - 1;
    for (int i = tid; i < 32 * 324; i += 256) {
        int c = i / 324, r = i % 324;
        int yy = r / 18, xx = r % 18;
        int gy = y0 + yy, gx = x0 + xx;
        float v = 0.0f;
        if (gy >= 0 && gy < 64 && gx >= 0 && gx < 64)
            v = xin[((size_t)b * CH + c) * NN + gy * 64 + gx];
        tile[c][r] = v;
    }
    __syncthreads();
    int py = tid >> 4, px = tid & 15;
    float acc[4];
    #pragma unroll
    for (int j = 0; j < 4; ++j) acc[j] = bsm[j];
    for (int i = 0; i < 32; ++i) {
        const float* tr = &tile[i][py * 18 + px];
        float v00 = tr[0],  v01 = tr[1],  v02 = tr[2];
        float v10 = tr[18], v11 = tr[19], v12 = tr[20];
        float v20 = tr[36], v21 = tr[37], v22 = tr[38];
        #pragma unroll
        for (int j = 0; j < 4; ++j) {
            const float* wj = &wsm[j * 288 + i * 9];
            acc[j] += v00 * wj[0] + v01 * wj[1] + v02 * wj[2]
                    + v10 * wj[3] + v11 * wj[4] + v12 * wj[5]
                    + v20 * wj[6] + v21 * wj[7] + v22 * wj[8];
        }
    }
    size_t base = (size_t)b * CH * NN + (size_t)(og * 4) * NN
                + (ty * 16 + py) * 64 + tx * 16 + px;
    #pragma unroll
    for (int j = 0; j < 4; ++j) {
        float r_ = fmaxf(acc[j], 0.0f);
        xout[base + j * NN] = r_;
        if (outx) outx[base + j * NN] = r_;
    }
}

// K6: final 3x3 conv 32->1 + b_out + corrected_map. channel-split 4x8, grid 256
__global__ void k6_convout(const float* __restrict__ xin, const float* __restrict__ w_out,
                           const float* __restrict__ b_out, const float* __restrict__ cmapf,
                           float* __restrict__ outp) {
    __shared__ float wsm[288];
    __shared__ float red[256];
    int tid = threadIdx.x;
    for (int i = tid; i < 288; i += 256) wsm[i] = w_out[i];
    int pxi = tid & 63, g = tid >> 6;
    int gid = blockIdx.x * 64 + pxi;   // B*N over 256 blocks
    int b = gid >> 12, hw = gid & 4095;
    int y = hw >> 6, x = hw & 63;
    __syncthreads();
    float acc = 0.0f;
    int c0 = g * 8;
    for (int i = c0; i < c0 + 8; ++i) {
        const float* xi = xin + ((size_t)b * CH + i) * NN;
        #pragma unroll
        for (int ky = 0; ky < 3; ++ky) {
            int gy = y + ky - 1;
            if (gy < 0 || gy > 63) continue;
            #pragma unroll
            for (int kx = 0; kx < 3; ++kx) {
                int gx = x + kx - 1;
                if (gx < 0 || gx > 63) continue;
                acc += xi[gy * 64 + gx] * wsm[i * 9 + ky * 3 + kx];
            }
        }
    }
    red[tid] = acc;
    __syncthreads();
    if (tid < 64) {
        float a = red[tid] + red[tid + 64] + red[tid + 128] + red[tid + 192]
                + b_out[0] + cmapf[gid];
        outp[OUT_O_OFF + gid] = a;
    }
}

extern "C" void kernel_launch(void* const* d_in, const int* in_sizes, int n_in,
                              void* d_out, int out_size, void* d_ws, size_t ws_size,
                              hipStream_t stream) {
    const float* f     = (const float*)d_in[0];
    const float* mapin = (const float*)d_in[1];
    const float* f_q   = (const float*)d_in[2];
    const float* f_k   = (const float*)d_in[3];
    const float* m_k   = (const float*)d_in[4];
    const float* wq    = (const float*)d_in[5];
    const float* wk    = (const float*)d_in[6];
    const float* w_in  = (const float*)d_in[7];
    const float* b_in  = (const float*)d_in[8];
    const float* w_mid = (const float*)d_in[9];
    const float* b_mid = (const float*)d_in[10];
    const float* w_out = (const float*)d_in[11];
    const float* b_out = (const float*)d_in[12];
    float* outp = (float*)d_out;
    float* ws = (float*)d_ws;

    float* PP    = ws + PP_OFF;
    float* Q4    = ws + Q4_OFF;
    float* K4    = ws + K4_OFF;
    float* CV    = ws + CV_OFF;
    float* CPSUM = ws + CPSUM_OFF;
    float* RMAP  = ws + RMAP_OFF;
    float* CMAPF = ws + CMAPF_OFF;
    float* T8    = ws + T8_OFF;
    float* XA    = ws + XA_OFF;
    float* XB    = ws + XB_OFF;

    k0_posproj<<<1, 64, 0, stream>>>(wq, wk, PP);
    k1_qk<<<256, 512, 0, stream>>>(f_q, f_k, wq, wk, PP, Q4, K4);
    k2a_colstats<<<BB * NQCH * 8, 256, 0, stream>>>(Q4, K4, CPSUM);
    k2b_cmerge<<<64, 256, 0, stream>>>(CPSUM, m_k, CV);
    k3a_scan<<<BB * 16 * 8, 256, 0, stream>>>(Q4, K4, CV, T8);
    k3b_merge<<<BB * NN / 4, 256, 0, stream>>>(T8, mapin, RMAP, CMAPF, outp);
    k4_conv1<<<512, 256, 0, stream>>>(f, RMAP, w_in, b_in, XA);
    k5_conv3<<<512, 256, 0, stream>>>(XA, w_mid + 0 * 9216, b_mid + 0 * 32, XB, (float*)0);
    k5_conv3<<<512, 256, 0, stream>>>(XB, w_mid + 1 * 9216, b_mid + 1 * 32, XA, (float*)0);
    k5_conv3<<<512, 256, 0, stream>>>(XA, w_mid + 2 * 9216, b_mid + 2 * 32, XB, outp + OUT_X_OFF);
    k6_convout<<<256, 256, 0, stream>>>(XB, w_out, b_out, CMAPF, outp);
}

// Round 12
// 206.410 us; speedup vs baseline: 1.1407x; 1.0826x over previous
//
#include <hip/hip_runtime.h>
#include <hip/hip_bf16.h>
#include <math.h>

// Problem constants
#define BB 4
#define CIN 64
#define CH 32
#define HH 64
#define WW 64
#define NN 4096           // H*W
#define MCH 4
#define NQCH 32           // q-chunks for column stats (chunk = 128 queries)
#define LOG2E 1.4426950408889634f
#define L2_10K 13.287712379549449f   // log2(10000)

// ws layout (floats). End = 2,278,400 floats = 8.69 MiB.
// (ws >= 10.16 MiB proven: rounds 1-3 ran a 10.16 MiB layout, bit-identical
// outputs across layout changes.)
// Temporal aliasing: CPSUM (k2a->k2b) and XA/XB (k4..k6) alias T8's region;
// T8 live only k3a->k3b, written after k2b, dead before k4.
#define Q4_OFF     1024       // 65536  (Q pre-scaled by LOG2E)
#define K4_OFF     66560      // 65536
#define CV_OFF     132096     // 16384  (c' in log2 domain)
#define RMAP_OFF   148480     // 16384
#define CMAPF_OFF  164864     // 16384
#define T8_OFF     181248     // 2097152 (16 chunks x 8 per query)
#define CPSUM_OFF  181248     // 524288 (aliases T8 head; dead before k3a)
#define XA_OFF     181248     // 524288 (aliases T8; written k4, after k3b)
#define XB_OFF     705536     // 524288 (aliases T8; written k5)

// out layout (FLOAT32 elements): x | out | corrected_map
#define OUT_X_OFF   0
#define OUT_O_OFF   524288
#define OUT_CM_OFF  540672

// compare-exchange (ascending)
#define CE(x, y) { float ce_lo = fminf(x, y); y = fmaxf(x, y); x = ce_lo; }

__device__ __forceinline__ float bilin32(const float* src, int b, int y, int x) {
    float sy = 0.5f * y - 0.25f;
    float sx = 0.5f * x - 0.25f;
    float fy0 = floorf(sy), fx0 = floorf(sx);
    int y0 = (int)fy0, x0 = (int)fx0;
    float fy = sy - fy0, fx = sx - fx0;
    int y0c = min(max(y0, 0), 31), y1c = min(max(y0 + 1, 0), 31);
    int x0c = min(max(x0, 0), 31), x1c = min(max(x0 + 1, 0), 31);
    const float* p = src + b * 1024;
    float v00 = p[y0c * 32 + x0c], v01 = p[y0c * 32 + x1c];
    float v10 = p[y1c * 32 + x0c], v11 = p[y1c * 32 + x1c];
    float v0 = v00 + fx * (v01 - v00);
    float v1 = v10 + fx * (v11 - v10);
    return v0 + fy * (v1 - v0);
}

// K1: Q/K projections with pos-embedding table computed IN-BLOCK (k0 fused).
// 512-thread blocks: threads 0..63 build the 4x4x64 pos table in LDS while
// the rest run channel partials; LDS reduce as before. grid = B*N/64 = 256.
__global__ __launch_bounds__(512) void k1_qk(
        const float* __restrict__ fq, const float* __restrict__ fk,
        const float* __restrict__ wq, const float* __restrict__ wk,
        float* __restrict__ Q4, float* __restrict__ K4) {
    __shared__ float wqs[256], wks[256];
    __shared__ float pp[1024];            // [4 groups][4 m][64 coord]
    __shared__ float red[512][9];
    int tid = threadIdx.x;
    if (tid < 256) { wqs[tid] = wq[tid]; wks[tid] = wk[tid]; }
    __syncthreads();

    if (tid < 64) {   // pos table for coordinate t = tid (exact, powf->exp2f)
        float coord = (float)(tid + 1);
        float qy[4] = {0,0,0,0}, qx[4] = {0,0,0,0}, ky[4] = {0,0,0,0}, kx[4] = {0,0,0,0};
        for (int c = 0; c < 32; ++c) {
            float e = (2.0f * (float)(c >> 1)) * (1.0f / 32.0f);
            float ang = coord * exp2f(-e * L2_10K);
            float pr = (c & 1) ? cosf(ang) : sinf(ang);
            #pragma unroll
            for (int m = 0; m < 4; ++m) {
                qy[m] += wqs[m * 64 + c] * pr;
                qx[m] += wqs[m * 64 + 32 + c] * pr;
                ky[m] += wks[m * 64 + c] * pr;
                kx[m] += wks[m * 64 + 32 + c] * pr;
            }
        }
        #pragma unroll
        for (int m = 0; m < 4; ++m) {
            pp[0 * 256 + m * 64 + tid] = qy[m];
            pp[1 * 256 + m * 64 + tid] = qx[m];
            pp[2 * 256 + m * 64 + tid] = ky[m];
            pp[3 * 256 + m * 64 + tid] = kx[m];
        }
    }

    int qi = tid & 63, g = tid >> 6;      // g = 0..7 channel group
    int gid = blockIdx.x * 64 + qi;
    int b = gid >> 12, hw = gid & 4095;
    const float* fqb = fq + (size_t)b * CIN * NN + hw;
    const float* fkb = fk + (size_t)b * CIN * NN + hw;
    float aq[4] = {0,0,0,0}, ak[4] = {0,0,0,0};
    int c0 = g * 8;
    #pragma unroll
    for (int c = c0; c < c0 + 8; ++c) {
        float vq = fqb[c * NN];
        float vk = fkb[c * NN];
        #pragma unroll
        for (int m = 0; m < 4; ++m) {
            aq[m] += wqs[m * 64 + c] * vq;
            ak[m] += wks[m * 64 + c] * vk;
        }
    }
    #pragma unroll
    for (int m = 0; m < 4; ++m) { red[tid][m] = aq[m]; red[tid][4 + m] = ak[m]; }
    __syncthreads();
    if (tid < 64) {
        int y = hw >> 6, x = hw & 63;
        float q4[4], k4[4];
        #pragma unroll
        for (int m = 0; m < 4; ++m) {
            float sq = 0.0f, sk = 0.0f;
            #pragma unroll
            for (int j = 0; j < 8; ++j) {
                sq += red[tid + 64 * j][m];
                sk += red[tid + 64 * j][4 + m];
            }
            q4[m] = LOG2E * (sq + pp[0 * 256 + m * 64 + y] + pp[1 * 256 + m * 64 + x]);
            k4[m] = sk + pp[2 * 256 + m * 64 + y] + pp[3 * 256 + m * 64 + x];
        }
        ((float4*)Q4)[gid] = make_float4(q4[0], q4[1], q4[2], q4[3]);
        ((float4*)K4)[gid] = make_float4(k4[0], k4[1], k4[2], k4[3]);
    }
}

// K2a: per-(b, q-chunk of 128) column sum of 2^(q'.k). Queries read via
// UNIFORM global address (scalar broadcast). grid = B*32*8.
__global__ void k2a_colstats(const float* __restrict__ Q4, const float* __restrict__ K4,
                             float* __restrict__ cpsum) {
    int blk = blockIdx.x;
    int kblk = blk & 7;   blk >>= 3;
    int qch  = blk & 31;  blk >>= 5;
    int b    = blk;
    int tid = threadIdx.x;
    const float4* Qg = (const float4*)Q4 + b * NN + qch * 128;  // uniform base
    int k0 = kblk * 512 + tid;
    float4 kva = ((const float4*)K4)[b * NN + k0];
    float4 kvb = ((const float4*)K4)[b * NN + k0 + 256];
    float sa = 0.0f, sb = 0.0f;
    #pragma unroll 8
    for (int i = 0; i < 128; ++i) {
        float4 q = Qg[i];   // uniform -> s_load broadcast
        float da = fmaf(q.x, kva.x, fmaf(q.y, kva.y, fmaf(q.z, kva.z, q.w * kva.w)));
        float db = fmaf(q.x, kvb.x, fmaf(q.y, kvb.y, fmaf(q.z, kvb.z, q.w * kvb.w)));
        sa += exp2f(da);
        sb += exp2f(db);
    }
    cpsum[(b * NQCH + qch) * NN + k0] = sa;
    cpsum[(b * NQCH + qch) * NN + k0 + 256] = sb;
}

// K2b: merge chunk sums -> c'[b][k] = LOG2E*(m_k_r - 1) - log2(colsum)
__global__ void k2b_cmerge(const float* __restrict__ cpsum,
                           const float* __restrict__ m_k, float* __restrict__ cvals) {
    int gid = blockIdx.x * 256 + threadIdx.x;  // B*N
    int b = gid >> 12, k = gid & 4095;
    float S = 0.0f;
    #pragma unroll
    for (int j = 0; j < NQCH; ++j) S += cpsum[(b * NQCH + j) * NN + k];
    float mk = bilin32(m_k, b, k >> 6, k & 63);
    cvals[gid] = LOG2E * (mk - 1.0f) - log2f(S);
}

// K3a: lane-per-query chunk scan v4 — 16 chunks of 256 keys (2x waves vs v3).
// Keys via uniform scalar loads; batch-8 dots + guarded Batcher sort +
// bitonic max-merge. grid = B*16*16 = 1024 blocks x 256 thr = 4096 waves.
__global__ __launch_bounds__(256) void k3a_scan(
        const float* __restrict__ Q4, const float* __restrict__ K4,
        const float* __restrict__ cvals, float* __restrict__ t8) {
    int blk = blockIdx.x;
    int kc = blk & 15;  blk >>= 4;
    int g4 = blk & 15;  blk >>= 4;
    int b  = blk;
    int tid = threadIdx.x;
    int wave = tid >> 6, lane = tid & 63;
    int qrow = (g4 * 4 + wave) * 64 + lane;
    float4 qv = ((const float4*)Q4)[b * NN + qrow];
    const float4* Kb = (const float4*)K4 + b * NN + kc * 256;   // uniform base
    const float* cb = cvals + b * NN + kc * 256;                // uniform base

    float t0=-1e30f,t1=-1e30f,t2=-1e30f,t3=-1e30f;
    float t4=-1e30f,t5=-1e30f,t6=-1e30f,t7=-1e30f;   // ascending; t0 = 8th

    #pragma unroll 2
    for (int i0 = 0; i0 < 256; i0 += 8) {
        float4 k0 = Kb[i0 + 0]; float4 k1 = Kb[i0 + 1];
        float4 k2 = Kb[i0 + 2]; float4 k3 = Kb[i0 + 3];
        float4 k4 = Kb[i0 + 4]; float4 k5 = Kb[i0 + 5];
        float4 k6 = Kb[i0 + 6]; float4 k7 = Kb[i0 + 7];
        float s0 = fmaf(qv.x,k0.x, fmaf(qv.y,k0.y, fmaf(qv.z,k0.z, qv.w*k0.w))) + cb[i0+0];
        float s1 = fmaf(qv.x,k1.x, fmaf(qv.y,k1.y, fmaf(qv.z,k1.z, qv.w*k1.w))) + cb[i0+1];
        float s2 = fmaf(qv.x,k2.x, fmaf(qv.y,k2.y, fmaf(qv.z,k2.z, qv.w*k2.w))) + cb[i0+2];
        float s3 = fmaf(qv.x,k3.x, fmaf(qv.y,k3.y, fmaf(qv.z,k3.z, qv.w*k3.w))) + cb[i0+3];
        float s4 = fmaf(qv.x,k4.x, fmaf(qv.y,k4.y, fmaf(qv.z,k4.z, qv.w*k4.w))) + cb[i0+4];
        float s5 = fmaf(qv.x,k5.x, fmaf(qv.y,k5.y, fmaf(qv.z,k5.z, qv.w*k5.w))) + cb[i0+5];
        float s6 = fmaf(qv.x,k6.x, fmaf(qv.y,k6.y, fmaf(qv.z,k6.z, qv.w*k6.w))) + cb[i0+6];
        float s7 = fmaf(qv.x,k7.x, fmaf(qv.y,k7.y, fmaf(qv.z,k7.z, qv.w*k7.w))) + cb[i0+7];
        float bm = fmaxf(fmaxf(fmaxf(s0,s1), fmaxf(s2,s3)),
                         fmaxf(fmaxf(s4,s5), fmaxf(s6,s7)));
        if (bm > t0) {
            // Batcher odd-even mergesort, 8 elems ascending (19 CE)
            CE(s0,s1); CE(s2,s3); CE(s4,s5); CE(s6,s7);
            CE(s0,s2); CE(s1,s3); CE(s4,s6); CE(s5,s7);
            CE(s1,s2); CE(s5,s6);
            CE(s0,s4); CE(s1,s5); CE(s2,s6); CE(s3,s7);
            CE(s2,s4); CE(s3,s5);
            CE(s1,s2); CE(s3,s4); CE(s5,s6);
            // bitonic max-merge: top-8 of {t} u {s} (both ascending)
            t0 = fmaxf(t0, s7); t1 = fmaxf(t1, s6); t2 = fmaxf(t2, s5); t3 = fmaxf(t3, s4);
            t4 = fmaxf(t4, s3); t5 = fmaxf(t5, s2); t6 = fmaxf(t6, s1); t7 = fmaxf(t7, s0);
            // result is bitonic -> 12-CE bitonic sort (ascending)
            CE(t0,t4); CE(t1,t5); CE(t2,t6); CE(t3,t7);
            CE(t0,t2); CE(t1,t3); CE(t4,t6); CE(t5,t7);
            CE(t0,t1); CE(t2,t3); CE(t4,t5); CE(t6,t7);
        }
    }
    float* o = t8 + ((size_t)(b * NN + qrow)) * 128 + kc * 8;
    o[0] = t0; o[1] = t1; o[2] = t2; o[3] = t3;
    o[4] = t4; o[5] = t5; o[6] = t6; o[7] = t7;
}

// K3b: merge 16 chunk-top8s (128 candidates) -> global top-8 -> cm/rmap.
// Lane holds 2 candidates sorted (hi >= lo); 8-round argmax-pop over hi.
__global__ void k3b_merge(const float* __restrict__ t8, const float* __restrict__ mapin,
                          float* __restrict__ rmap, float* __restrict__ cmapf,
                          float* __restrict__ outp) {
    int tid = threadIdx.x;
    int qid = blockIdx.x * 4 + (tid >> 6);   // 0 .. B*N-1
    int lane = tid & 63;
    float va = t8[(size_t)qid * 128 + lane];
    float vb = t8[(size_t)qid * 128 + 64 + lane];
    float hi = fmaxf(va, vb), lo = fminf(va, vb);
    float sm = 0.0f;
    #pragma unroll
    for (int r = 0; r < 8; ++r) {
        float m = hi;
        int ln = lane;
        #pragma unroll
        for (int off = 32; off >= 1; off >>= 1) {
            float om = __shfl_xor(m, off);
            int ol = __shfl_xor(ln, off);
            if (om > m || (om == m && ol < ln)) { m = om; ln = ol; }
        }
        sm += exp2f(m);
        if (lane == ln) { hi = lo; lo = -1e30f; }
    }
    if (lane == 0) {
        float cmv = sm * 0.125f;
        int b = qid >> 12, hw = qid & 4095;
        float mr = bilin32(mapin, b, hw >> 6, hw & 63);
        float cm = cmv * mr + mr;
        float rm = 1.0f / (1.0f + __expf(cm));
        rmap[qid] = rm;
        cmapf[qid] = cm;
        outp[OUT_CM_OFF + qid] = cm;
    }
}

// K4: x1 = conv1x1(rmap*f, w_in) + b_in. og-split 8 -> grid 512
__global__ void k4_conv1(const float* __restrict__ f, const float* __restrict__ rmap,
                         const float* __restrict__ w_in, const float* __restrict__ b_in,
                         float* __restrict__ xout) {
    __shared__ float ws_[1024];
    __shared__ float bs[32];
    int tid = threadIdx.x;
    for (int i = tid; i < 1024; i += 256) ws_[i] = w_in[i];
    if (tid < 32) bs[tid] = b_in[tid];
    __syncthreads();
    int gid = blockIdx.x * 256 + tid;      // b(2b) og(3b) hw(12b)
    int hw = gid & 4095;
    int og = (gid >> 12) & 7;
    int b  = gid >> 15;
    float rm = rmap[b * NN + hw];
    float acc[4];
    #pragma unroll
    for (int j = 0; j < 4; ++j) acc[j] = bs[og * 4 + j];
    const float* fb = f + (size_t)b * CH * NN + hw;
    for (int i = 0; i < 32; ++i) {
        float v = fb[i * NN] * rm;
        #pragma unroll
        for (int j = 0; j < 4; ++j) acc[j] += ws_[(og * 4 + j) * 32 + i] * v;
    }
    float* xo = xout + (size_t)b * CH * NN + (og * 4) * NN + hw;
    #pragma unroll
    for (int j = 0; j < 4; ++j) xo[j * NN] = acc[j];
}

// K5: 3x3 conv 32->32 (+bias, relu). og-split 8 -> grid = b*ty*tx*og = 512
__global__ void k5_conv3(const float* __restrict__ xin, const float* __restrict__ w,
                         const float* __restrict__ bias, float* __restrict__ xout,
                         float* __restrict__ outx) {
    __shared__ float tile[32][324];   // 18x18 per channel
    __shared__ float wsm[1152];       // 4 o x 32 i x 9
    __shared__ float bsm[4];
    int blk = blockIdx.x;
    int og = blk & 7;  blk >>= 3;
    int tx = blk & 3;  blk >>= 2;
    int ty = blk & 3;  blk >>= 2;
    int b  = blk;
    int tid = threadIdx.x;
    for (int i = tid; i < 1152; i += 256) wsm[i] = w[og * 1152 + i];
    if (tid < 4) bsm[tid] = bias[og * 4 + tid];
    int y0 = ty * 16 - 1, x0 = tx * 16 - 1;
    for (int i = tid; i < 32 * 324; i += 256) {
        int c = i / 324, r = i % 324;
        int yy = r / 18, xx = r % 18;
        int gy = y0 + yy, gx = x0 + xx;
        float v = 0.0f;
        if (gy >= 0 && gy < 64 && gx >= 0 && gx < 64)
            v = xin[((size_t)b * CH + c) * NN + gy * 64 + gx];
        tile[c][r] = v;
    }
    __syncthreads();
    int py = tid >> 4, px = tid & 15;
    float acc[4];
    #pragma unroll
    for (int j = 0; j < 4; ++j) acc[j] = bsm[j];
    for (int i = 0; i < 32; ++i) {
        const float* tr = &tile[i][py * 18 + px];
        float v00 = tr[0],  v01 = tr[1],  v02 = tr[2];
        float v10 = tr[18], v11 = tr[19], v12 = tr[20];
        float v20 = tr[36], v21 = tr[37], v22 = tr[38];
        #pragma unroll
        for (int j = 0; j < 4; ++j) {
            const float* wj = &wsm[j * 288 + i * 9];
            acc[j] += v00 * wj[0] + v01 * wj[1] + v02 * wj[2]
                    + v10 * wj[3] + v11 * wj[4] + v12 * wj[5]
                    + v20 * wj[6] + v21 * wj[7] + v22 * wj[8];
        }
    }
    size_t base = (size_t)b * CH * NN + (size_t)(og * 4) * NN
                + (ty * 16 + py) * 64 + tx * 16 + px;
    #pragma unroll
    for (int j = 0; j < 4; ++j) {
        float r_ = fmaxf(acc[j], 0.0f);
        xout[base + j * NN] = r_;
        if (outx) outx[base + j * NN] = r_;
    }
}

// K6: final 3x3 conv 32->1 + b_out + corrected_map. channel-split 4x8, grid 256
__global__ void k6_convout(const float* __restrict__ xin, const float* __restrict__ w_out,
                           const float* __restrict__ b_out, const float* __restrict__ cmapf,
                           float* __restrict__ outp) {
    __shared__ float wsm[288];
    __shared__ float red[256];
    int tid = threadIdx.x;
    for (int i = tid; i < 288; i += 256) wsm[i] = w_out[i];
    int pxi = tid & 63, g = tid >> 6;
    int gid = blockIdx.x * 64 + pxi;   // B*N over 256 blocks
    int b = gid >> 12, hw = gid & 4095;
    int y = hw >> 6, x = hw & 63;
    __syncthreads();
    float acc = 0.0f;
    int c0 = g * 8;
    for (int i = c0; i < c0 + 8; ++i) {
        const float* xi = xin + ((size_t)b * CH + i) * NN;
        #pragma unroll
        for (int ky = 0; ky < 3; ++ky) {
            int gy = y + ky - 1;
            if (gy < 0 || gy > 63) continue;
            #pragma unroll
            for (int kx = 0; kx < 3; ++kx) {
                int gx = x + kx - 1;
                if (gx < 0 || gx > 63) continue;
                acc += xi[gy * 64 + gx] * wsm[i * 9 + ky * 3 + kx];
            }
        }
    }
    red[tid] = acc;
    __syncthreads();
    if (tid < 64) {
        float a = red[tid] + red[tid + 64] + red[tid + 128] + red[tid + 192]
                + b_out[0] + cmapf[gid];
        outp[OUT_O_OFF + gid] = a;
    }
}

extern "C" void kernel_launch(void* const* d_in, const int* in_sizes, int n_in,
                              void* d_out, int out_size, void* d_ws, size_t ws_size,
                              hipStream_t stream) {
    const float* f     = (const float*)d_in[0];
    const float* mapin = (const float*)d_in[1];
    const float* f_q   = (const float*)d_in[2];
    const float* f_k   = (const float*)d_in[3];
    const float* m_k   = (const float*)d_in[4];
    const float* wq    = (const float*)d_in[5];
    const float* wk    = (const float*)d_in[6];
    const float* w_in  = (const float*)d_in[7];
    const float* b_in  = (const float*)d_in[8];
    const float* w_mid = (const float*)d_in[9];
    const float* b_mid = (const float*)d_in[10];
    const float* w_out = (const float*)d_in[11];
    const float* b_out = (const float*)d_in[12];
    float* outp = (float*)d_out;
    float* ws = (float*)d_ws;

    float* Q4    = ws + Q4_OFF;
    float* K4    = ws + K4_OFF;
    float* CV    = ws + CV_OFF;
    float* CPSUM = ws + CPSUM_OFF;
    float* RMAP  = ws + RMAP_OFF;
    float* CMAPF = ws + CMAPF_OFF;
    float* T8    = ws + T8_OFF;
    float* XA    = ws + XA_OFF;
    float* XB    = ws + XB_OFF;

    k1_qk<<<256, 512, 0, stream>>>(f_q, f_k, wq, wk, Q4, K4);
    k2a_colstats<<<BB * NQCH * 8, 256, 0, stream>>>(Q4, K4, CPSUM);
    k2b_cmerge<<<64, 256, 0, stream>>>(CPSUM, m_k, CV);
    k3a_scan<<<BB * 16 * 16, 256, 0, stream>>>(Q4, K4, CV, T8);
    k3b_merge<<<BB * NN / 4, 256, 0, stream>>>(T8, mapin, RMAP, CMAPF, outp);
    k4_conv1<<<512, 256, 0, stream>>>(f, RMAP, w_in, b_in, XA);
    k5_conv3<<<512, 256, 0, stream>>>(XA, w_mid + 0 * 9216, b_mid + 0 * 32, XB, (float*)0);
    k5_conv3<<<512, 256, 0, stream>>>(XB, w_mid + 1 * 9216, b_mid + 1 * 32, XA, (float*)0);
    k5_conv3<<<512, 256, 0, stream>>>(XA, w_mid + 2 * 9216, b_mid + 2 * 32, XB, outp + OUT_X_OFF);
    k6_convout<<<256, 256, 0, stream>>>(XB, w_out, b_out, CMAPF, outp);
}